// Round 1
// 387.313 us; speedup vs baseline: 1.2012x; 1.2012x over previous
//
#include <hip/hip_runtime.h>
#include <stdint.h>

#define B_DIM 4096
#define IN_SZ 1024
#define HID   2048
#define D_DIM 3072   // K = IN_SZ + HID
#define BM 256       // batch rows per block
#define BN 64        // h-columns per block (x4 gates = 256 logical cols)
#define BK 64        // K-step (bf16 elems)
#define NT (D_DIM / BK)   // 48

typedef float  f32x4  __attribute__((ext_vector_type(4)));
typedef short  short8 __attribute__((ext_vector_type(8)));

__device__ __forceinline__ unsigned short f2bf(float f) {
    union { float f; unsigned u; } v; v.f = f;
    unsigned u = v.u + 0x7fffu + ((v.u >> 16) & 1u);   // RNE
    return (unsigned short)(u >> 16);
}

__device__ __forceinline__ void async_load16(const void* g, void* l) {
    __builtin_amdgcn_global_load_lds(
        (const __attribute__((address_space(1))) unsigned int*)g,
        (__attribute__((address_space(3))) unsigned int*)l,
        16, 0, 0);
}

__device__ __forceinline__ float sigm(float x) {
    return 1.0f / (1.0f + __expf(-x));
}
__device__ __forceinline__ float tanh_f(float x) {
    return 1.0f - 2.0f / (__expf(2.0f * x) + 1.0f);
}

// ---- single prepass: concat(x,h)->bf16 [B][D]  and  concat(W_i..W_o)->bf16 [4H][D] ----
__global__ __launch_bounds__(256)
void convert_all(const float* __restrict__ x, const float* __restrict__ h,
                 const float* __restrict__ W0, const float* __restrict__ W1,
                 const float* __restrict__ W2, const float* __restrict__ W3,
                 unsigned short* __restrict__ Abf, unsigned short* __restrict__ Wbf) {
    const int NA = B_DIM * D_DIM / 8;        // 1,572,864
    const int NW = 4 * HID * D_DIM / 8;      // 3,145,728
    int idx = blockIdx.x * blockDim.x + threadIdx.x;
    const float* src;
    unsigned short* dst;
    if (idx < NA) {
        const int C8 = D_DIM / 8;            // 384
        int b = idx / C8, c8 = idx - b * C8;
        src = (c8 < IN_SZ / 8) ? x + (size_t)b * IN_SZ + c8 * 8
                               : h + (size_t)b * HID + (c8 - IN_SZ / 8) * 8;
        dst = Abf + (size_t)idx * 8;
    } else {
        int wi = idx - NA;
        if (wi >= NW) return;
        const int PG = HID * D_DIM / 8;      // 786,432 per gate
        int g = wi / PG, r = wi - g * PG;
        const float* W = (g == 0) ? W0 : (g == 1) ? W1 : (g == 2) ? W2 : W3;
        src = W + (size_t)r * 8;
        dst = Wbf + (size_t)wi * 8;
    }
    float4 v0 = ((const float4*)src)[0];
    float4 v1 = ((const float4*)src)[1];
    short8 o;
    o[0] = (short)f2bf(v0.x); o[1] = (short)f2bf(v0.y);
    o[2] = (short)f2bf(v0.z); o[3] = (short)f2bf(v0.w);
    o[4] = (short)f2bf(v1.x); o[5] = (short)f2bf(v1.y);
    o[6] = (short)f2bf(v1.z); o[7] = (short)f2bf(v1.w);
    *(short8*)dst = o;
}

// ---------- 8-phase-template helpers ----------
template <int IB>
__device__ __forceinline__ void read_a(short8 (&aR)[4][2], const char* smA,
                                       int aBase, int sw0, int sw1) {
#pragma unroll
    for (int i = 0; i < 4; ++i) {
        aR[i][0] = *(const short8*)(smA + aBase + (IB + i) * 2048 + sw0);
        aR[i][1] = *(const short8*)(smA + aBase + (IB + i) * 2048 + sw1);
    }
}

template <int JB>
__device__ __forceinline__ void read_b(short8 (&bR)[4][2], const char* smB,
                                       int bBase, int sw0, int sw1) {
#pragma unroll
    for (int j = 0; j < 2; ++j) {
        bR[JB + j][0] = *(const short8*)(smB + bBase + (JB + j) * 2048 + sw0);
        bR[JB + j][1] = *(const short8*)(smB + bBase + (JB + j) * 2048 + sw1);
    }
}

template <int IB, int JB>
__device__ __forceinline__ void mfma_quad(f32x4 (&acc)[8][4], const short8 (&aR)[4][2],
                                          const short8 (&bR)[4][2]) {
#pragma unroll
    for (int i = 0; i < 4; ++i)
#pragma unroll
        for (int j = 0; j < 2; ++j)
#pragma unroll
            for (int s = 0; s < 2; ++s)
                acc[IB + i][JB + j] = __builtin_amdgcn_mfma_f32_16x16x32_bf16(
                    aR[i][s], bR[JB + j][s], acc[IB + i][JB + j], 0, 0, 0);
}

// ---- fused gate-GEMM + LSTM epilogue, 256x(64h x 4gates) tile, BK=64, 8 waves ----
// Column mapping: col = h_hi*64 + gate*16 + h_lo  (h = h0 + h_hi*16 + h_lo).
// Wave (wm,wn): rows [wm*128,+128) x cols [wn*64,+64) -> n-frag j == gate j, so all
// 4 gates of an (m,h) land in the same lane -> register-local LSTM epilogue.
// LDS: 2 x (A 32K | B 32K) = 128 KiB, tiles stored [row][64] bf16 (128 B rows) with
// slot ^= row&7 XOR swizzle (applied on the pre-swizzled global staging source AND
// the ds_read offset -> conflict-free ds_read_b128).
__global__ __launch_bounds__(512, 2)
void lstm_gemm(const unsigned short* __restrict__ Abf,   // [B][D] bf16
               const unsigned short* __restrict__ Wbf,   // [4H][D] bf16
               const float* __restrict__ b_i, const float* __restrict__ b_f,
               const float* __restrict__ b_c, const float* __restrict__ b_o,
               const float* __restrict__ c_prev,
               float* __restrict__ h_out, float* __restrict__ c_out) {
    extern __shared__ char sm[];   // 131072 B

    const int tid  = threadIdx.x;
    const int lane = tid & 63;
    const int wave = tid >> 6;          // 0..7
    const int wm   = wave >> 2;         // 0..1
    const int wn   = wave & 3;          // 0..3
    const int l16  = lane & 15;
    const int quad = lane >> 4;
    const int r7   = l16 & 7;

    const int m0 = blockIdx.x * BM;
    const int h0 = blockIdx.y * BN;

    // staging: instruction (wave,i) covers tile rows (wave*4+i)*8 .. +8 (128 B each)
    const int g8 = lane >> 3;           // row within octet
    const int sl = (lane & 7) ^ g8;     // pre-swizzled source slot (involution)
    const unsigned short* srcA[4];
    const unsigned short* srcB[4];
#pragma unroll
    for (int i = 0; i < 4; ++i) {
        const int rt = (wave * 4 + i) * 8 + g8;        // tile row 0..255
        srcA[i] = Abf + (size_t)(m0 + rt) * D_DIM + sl * 8;
        // B tile row -> W global row: gate=(rt>>4)&3, h = h0 + (rt>>6)*16 + (rt&15)
        const int grow = ((rt >> 4) & 3) * HID + h0 + (rt >> 6) * 16 + (rt & 15);
        srcB[i] = Wbf + (size_t)grow * D_DIM + sl * 8;
    }
    const int chunk = wave * 4096;      // per-wave stage region (+i*1024)

    // ds_read offsets: addr = row*128 + ((s*4+quad)^ (row&7))*16, row&7 == l16&7
    const int aBase = (wm * 128 + l16) * 128;
    const int bBase = (wn * 64  + l16) * 128;
    const int sw0 = ((0 * 4 + quad) ^ r7) * 16;
    const int sw1 = ((1 * 4 + quad) ^ r7) * 16;

    f32x4 acc[8][4] = {};
    short8 aR[4][2], bR[4][2];

    // ---- prologue: stage K-tile 0 into buf 0 ----
#pragma unroll
    for (int i = 0; i < 4; ++i) {
        async_load16(srcA[i], sm + chunk + i * 1024);
        async_load16(srcB[i], sm + 32768 + chunk + i * 1024);
    }
    asm volatile("s_waitcnt vmcnt(0)" ::: "memory");
    __builtin_amdgcn_s_barrier();

    for (int kt = 0; kt < NT; ++kt) {
        const char* smA = sm + (kt & 1) * 65536;
        const char* smB = smA + 32768;
        char* smAn = sm + ((kt + 1) & 1) * 65536;
        char* smBn = smAn + 32768;
        const int koff = (kt + 1) * BK;
        const bool pf = (kt + 1 < NT);

        // ================= phase 1: m-half0 x gates{0,1} =================
        if (pf) {
#pragma unroll
            for (int i = 0; i < 4; ++i)
                async_load16(srcA[i] + koff, smAn + chunk + i * 1024);
        }
        read_a<0>(aR, smA, aBase, sw0, sw1);
        read_b<0>(bR, smB, bBase, sw0, sw1);
        __builtin_amdgcn_s_barrier();
        asm volatile("s_waitcnt lgkmcnt(0)" ::: "memory");
        __builtin_amdgcn_sched_barrier(0);
        __builtin_amdgcn_s_setprio(1);
        mfma_quad<0, 0>(acc, aR, bR);
        __builtin_amdgcn_s_setprio(0);
        __builtin_amdgcn_s_barrier();

        // ================= phase 2: m-half0 x gates{2,3} =================
        if (pf) {
#pragma unroll
            for (int i = 0; i < 4; ++i)
                async_load16(srcB[i] + koff, smBn + chunk + i * 1024);
        }
        read_b<2>(bR, smB, bBase, sw0, sw1);
        __builtin_amdgcn_s_barrier();
        asm volatile("s_waitcnt lgkmcnt(0)" ::: "memory");
        __builtin_amdgcn_sched_barrier(0);
        __builtin_amdgcn_s_setprio(1);
        mfma_quad<0, 2>(acc, aR, bR);
        __builtin_amdgcn_s_setprio(0);
        __builtin_amdgcn_s_barrier();

        // ================= phase 3: m-half1 x gates{2,3} =================
        read_a<4>(aR, smA, aBase, sw0, sw1);
        __builtin_amdgcn_s_barrier();
        asm volatile("s_waitcnt lgkmcnt(0)" ::: "memory");
        __builtin_amdgcn_sched_barrier(0);
        __builtin_amdgcn_s_setprio(1);
        mfma_quad<4, 2>(acc, aR, bR);
        __builtin_amdgcn_s_setprio(0);
        __builtin_amdgcn_s_barrier();

        // ================= phase 4: m-half1 x gates{0,1} =================
        __builtin_amdgcn_sched_barrier(0);
        __builtin_amdgcn_s_setprio(1);
        mfma_quad<4, 0>(acc, aR, bR);
        __builtin_amdgcn_s_setprio(0);
        asm volatile("s_waitcnt vmcnt(0)" ::: "memory");   // stages issued 2.5-3.5 phases ago
        __builtin_amdgcn_s_barrier();
    }

    // ---- epilogue: C layout col = lane&15, row = quad*4 + reg ----
    const int h = h0 + wn * 16 + l16;
    const float biv = b_i[h], bfv = b_f[h], bcv = b_c[h], bov = b_o[h];
    const int mb = m0 + wm * 128 + quad * 4;
#pragma unroll
    for (int i = 0; i < 8; ++i) {
#pragma unroll
        for (int r = 0; r < 4; ++r) {
            const int m = mb + i * 16 + r;
            const size_t off = (size_t)m * HID + h;
            const float gi = acc[i][0][r] + biv;
            const float gf = acc[i][1][r] + bfv;
            const float gc = acc[i][2][r] + bcv;
            const float go = acc[i][3][r] + bov;
            const float it = sigm(gi), ft = sigm(gf);
            const float gt = tanh_f(gc), ot = sigm(go);
            const float c = ft * c_prev[off] + it * gt;
            h_out[off] = ot * tanh_f(c);
            c_out[off] = c;
        }
    }
}

extern "C" void kernel_launch(void* const* d_in, const int* in_sizes, int n_in,
                              void* d_out, int out_size, void* d_ws, size_t ws_size,
                              hipStream_t stream) {
    const float* x_t    = (const float*)d_in[0];
    const float* h_prev = (const float*)d_in[1];
    const float* c_prev = (const float*)d_in[2];
    const float* W_i = (const float*)d_in[3];
    const float* b_i = (const float*)d_in[4];
    const float* W_f = (const float*)d_in[5];
    const float* b_f = (const float*)d_in[6];
    const float* W_c = (const float*)d_in[7];
    const float* b_c = (const float*)d_in[8];
    const float* W_o = (const float*)d_in[9];
    const float* b_o = (const float*)d_in[10];
    float* out = (float*)d_out;

    unsigned short* Abf = (unsigned short*)d_ws;                       // 25,165,824 B
    unsigned short* Wbf = (unsigned short*)((char*)d_ws + (size_t)B_DIM * D_DIM * 2);
    // total ws use: 75,497,472 B

    static bool s_attr = false;
    if (!s_attr) {
        (void)hipFuncSetAttribute((const void*)lstm_gemm,
                                  hipFuncAttributeMaxDynamicSharedMemorySize, 131072);
        s_attr = true;
    }

    {
        const int n = (B_DIM * D_DIM + 4 * HID * D_DIM) / 8;   // 4,718,592
        convert_all<<<n / 256, 256, 0, stream>>>(x_t, h_prev, W_i, W_f, W_c, W_o,
                                                 Abf, Wbf);
    }
    dim3 grid(B_DIM / BM, HID / BN);   // 16 x 32
    lstm_gemm<<<grid, 512, 131072, stream>>>(Abf, Wbf, b_i, b_f, b_c, b_o, c_prev,
                                             out, out + (size_t)B_DIM * HID);
}

// Round 2
// 385.330 us; speedup vs baseline: 1.2074x; 1.0051x over previous
//
#include <hip/hip_runtime.h>
#include <stdint.h>

#define B_DIM 4096
#define IN_SZ 1024
#define HID   2048
#define D_DIM 3072   // K = IN_SZ + HID
#define BM 256       // batch rows per block
#define BN 64        // h-columns per block (x4 gates = 256 logical cols)
#define BK 64        // K-step (bf16 elems)
#define NT (D_DIM / BK)   // 48

typedef float  f32x4  __attribute__((ext_vector_type(4)));
typedef short  short8 __attribute__((ext_vector_type(8)));

__device__ __forceinline__ unsigned short f2bf(float f) {
    union { float f; unsigned u; } v; v.f = f;
    unsigned u = v.u + 0x7fffu + ((v.u >> 16) & 1u);   // RNE
    return (unsigned short)(u >> 16);
}

__device__ __forceinline__ void async_load16(const void* g, void* l) {
    __builtin_amdgcn_global_load_lds(
        (const __attribute__((address_space(1))) unsigned int*)g,
        (__attribute__((address_space(3))) unsigned int*)l,
        16, 0, 0);
}

__device__ __forceinline__ float sigm(float x) {
    return 1.0f / (1.0f + __expf(-x));
}
__device__ __forceinline__ float tanh_f(float x) {
    return 1.0f - 2.0f / (__expf(2.0f * x) + 1.0f);
}

// ---- single prepass: concat(x,h)->bf16 [B][D]  and  concat(W_i..W_o)->bf16 [4H][D] ----
__global__ __launch_bounds__(256)
void convert_all(const float* __restrict__ x, const float* __restrict__ h,
                 const float* __restrict__ W0, const float* __restrict__ W1,
                 const float* __restrict__ W2, const float* __restrict__ W3,
                 unsigned short* __restrict__ Abf, unsigned short* __restrict__ Wbf) {
    const int NA = B_DIM * D_DIM / 8;        // 1,572,864
    const int NW = 4 * HID * D_DIM / 8;      // 3,145,728
    int idx = blockIdx.x * blockDim.x + threadIdx.x;
    const float* src;
    unsigned short* dst;
    if (idx < NA) {
        const int C8 = D_DIM / 8;            // 384
        int b = idx / C8, c8 = idx - b * C8;
        src = (c8 < IN_SZ / 8) ? x + (size_t)b * IN_SZ + c8 * 8
                               : h + (size_t)b * HID + (c8 - IN_SZ / 8) * 8;
        dst = Abf + (size_t)idx * 8;
    } else {
        int wi = idx - NA;
        if (wi >= NW) return;
        const int PG = HID * D_DIM / 8;      // 786,432 per gate
        int g = wi / PG, r = wi - g * PG;
        const float* W = (g == 0) ? W0 : (g == 1) ? W1 : (g == 2) ? W2 : W3;
        src = W + (size_t)r * 8;
        dst = Wbf + (size_t)wi * 8;
    }
    float4 v0 = ((const float4*)src)[0];
    float4 v1 = ((const float4*)src)[1];
    short8 o;
    o[0] = (short)f2bf(v0.x); o[1] = (short)f2bf(v0.y);
    o[2] = (short)f2bf(v0.z); o[3] = (short)f2bf(v0.w);
    o[4] = (short)f2bf(v1.x); o[5] = (short)f2bf(v1.y);
    o[6] = (short)f2bf(v1.z); o[7] = (short)f2bf(v1.w);
    *(short8*)dst = o;
}

// ---------- phase helpers ----------
template <int IB>
__device__ __forceinline__ void read_a(short8 (&aR)[4][2], const char* smA,
                                       int aBase, int sw0, int sw1) {
#pragma unroll
    for (int i = 0; i < 4; ++i) {
        aR[i][0] = *(const short8*)(smA + aBase + (IB + i) * 2048 + sw0);
        aR[i][1] = *(const short8*)(smA + aBase + (IB + i) * 2048 + sw1);
    }
}

template <int JB>
__device__ __forceinline__ void read_b(short8 (&bR)[4][2], const char* smB,
                                       int bBase, int sw0, int sw1) {
#pragma unroll
    for (int j = 0; j < 2; ++j) {
        bR[JB + j][0] = *(const short8*)(smB + bBase + (JB + j) * 2048 + sw0);
        bR[JB + j][1] = *(const short8*)(smB + bBase + (JB + j) * 2048 + sw1);
    }
}

template <int IB, int JB>
__device__ __forceinline__ void mfma_quad(f32x4 (&acc)[8][4], const short8 (&aR)[4][2],
                                          const short8 (&bR)[4][2]) {
#pragma unroll
    for (int i = 0; i < 4; ++i)
#pragma unroll
        for (int j = 0; j < 2; ++j)
#pragma unroll
            for (int s = 0; s < 2; ++s)
                acc[IB + i][JB + j] = __builtin_amdgcn_mfma_f32_16x16x32_bf16(
                    aR[i][s], bR[JB + j][s], acc[IB + i][JB + j], 0, 0, 0);
}

// One K-tile = 4 phases. Rolling half-tile prefetch, depth 2 tiles:
//   phase 3 stages B[kt+2] into the CURRENT buffer's B half (released at phase 2's barrier)
//   phase 4 stages A[kt+2] into the CURRENT buffer's A half (released at phase 3's barrier)
//   end-of-tile wait = vmcnt(8): retires B[kt+1],A[kt+1] (issued ~6 phases earlier),
//   keeps B[kt+2],A[kt+2] (8 loads) in flight -> VMEM queue never drains in main loop.
// MODE: 1 = steady (stage + vmcnt(8)), 0 = tile NT-2 (no stage, vmcnt(0)), -1 = last tile.
template <int MODE>
__device__ __forceinline__ void tile_body(
    f32x4 (&acc)[8][4], short8 (&aR)[4][2], short8 (&bR)[4][2],
    const char* smA, const char* smB,
    const unsigned short* const* srcA, const unsigned short* const* srcB,
    int koff, int chunk, int aBase, int bBase, int sw0, int sw1) {
    char* stA = (char*)smA + chunk;   // stage dest for A[kt+2] (same buffer, released half)
    char* stB = (char*)smB + chunk;

    // ================= phase 1: m-half0 x gates{0,1} =================
    read_a<0>(aR, smA, aBase, sw0, sw1);
    read_b<0>(bR, smB, bBase, sw0, sw1);
    __builtin_amdgcn_s_barrier();
    asm volatile("s_waitcnt lgkmcnt(0)" ::: "memory");
    __builtin_amdgcn_sched_barrier(0);
    __builtin_amdgcn_s_setprio(1);
    mfma_quad<0, 0>(acc, aR, bR);
    __builtin_amdgcn_s_setprio(0);
    __builtin_amdgcn_s_barrier();

    // ================= phase 2: m-half0 x gates{2,3} =================
    read_b<2>(bR, smB, bBase, sw0, sw1);
    __builtin_amdgcn_s_barrier();
    asm volatile("s_waitcnt lgkmcnt(0)" ::: "memory");
    __builtin_amdgcn_sched_barrier(0);
    __builtin_amdgcn_s_setprio(1);
    mfma_quad<0, 2>(acc, aR, bR);
    __builtin_amdgcn_s_setprio(0);
    __builtin_amdgcn_s_barrier();
    // B half of this buffer now fully consumed by all waves.

    // ================= phase 3: m-half1 x gates{2,3} =================
    if (MODE == 1) {
#pragma unroll
        for (int i = 0; i < 4; ++i)
            async_load16(srcB[i] + koff, stB + i * 1024);
    }
    read_a<4>(aR, smA, aBase, sw0, sw1);
    __builtin_amdgcn_s_barrier();
    asm volatile("s_waitcnt lgkmcnt(0)" ::: "memory");
    __builtin_amdgcn_sched_barrier(0);
    __builtin_amdgcn_s_setprio(1);
    mfma_quad<4, 2>(acc, aR, bR);
    __builtin_amdgcn_s_setprio(0);
    __builtin_amdgcn_s_barrier();
    // A half of this buffer now fully consumed by all waves.

    // ================= phase 4: m-half1 x gates{0,1} =================
    if (MODE == 1) {
#pragma unroll
        for (int i = 0; i < 4; ++i)
            async_load16(srcA[i] + koff, stA + i * 1024);
    }
    __builtin_amdgcn_sched_barrier(0);
    __builtin_amdgcn_s_setprio(1);
    mfma_quad<4, 0>(acc, aR, bR);
    __builtin_amdgcn_s_setprio(0);
    if (MODE == 1) {
        asm volatile("s_waitcnt vmcnt(8)" ::: "memory");   // counted: keep 8 newest in flight
    } else if (MODE == 0) {
        asm volatile("s_waitcnt vmcnt(0)" ::: "memory");   // drain for final tile's data
    }
    if (MODE >= 0) __builtin_amdgcn_s_barrier();
}

// ---- fused gate-GEMM + LSTM epilogue, 256x(64h x 4gates) tile, BK=64, 8 waves ----
// Column mapping: col = h_hi*64 + gate*16 + h_lo -> all 4 gates of an (m,h) share a lane.
// LDS: 2 x (A 32K | B 32K) = 128 KiB, [row][64] bf16 rows (128 B) with slot^=row&7 XOR
// swizzle on BOTH the pre-swizzled global staging source and the ds_read offset.
__global__ __launch_bounds__(512, 2)
void lstm_gemm(const unsigned short* __restrict__ Abf,   // [B][D] bf16
               const unsigned short* __restrict__ Wbf,   // [4H][D] bf16
               const float* __restrict__ b_i, const float* __restrict__ b_f,
               const float* __restrict__ b_c, const float* __restrict__ b_o,
               const float* __restrict__ c_prev,
               float* __restrict__ h_out, float* __restrict__ c_out) {
    extern __shared__ char sm[];   // 131072 B

    const int tid  = threadIdx.x;
    const int lane = tid & 63;
    const int wave = tid >> 6;          // 0..7
    const int wm   = wave >> 2;         // 0..1
    const int wn   = wave & 3;          // 0..3
    const int l16  = lane & 15;
    const int quad = lane >> 4;
    const int r7   = l16 & 7;

    const int m0 = blockIdx.x * BM;
    const int h0 = blockIdx.y * BN;

    // staging: instruction (wave,i) covers tile rows (wave*4+i)*8 .. +8 (128 B each)
    const int g8 = lane >> 3;           // row within octet
    const int sl = (lane & 7) ^ g8;     // pre-swizzled source slot (involution)
    const unsigned short* srcA[4];
    const unsigned short* srcB[4];
#pragma unroll
    for (int i = 0; i < 4; ++i) {
        const int rt = (wave * 4 + i) * 8 + g8;        // tile row 0..255
        srcA[i] = Abf + (size_t)(m0 + rt) * D_DIM + sl * 8;
        // B tile row -> W global row: gate=(rt>>4)&3, h = h0 + (rt>>6)*16 + (rt&15)
        const int grow = ((rt >> 4) & 3) * HID + h0 + (rt >> 6) * 16 + (rt & 15);
        srcB[i] = Wbf + (size_t)grow * D_DIM + sl * 8;
    }
    const int chunk = wave * 4096;      // per-wave stage region (+i*1024)

    // ds_read offsets: addr = row*128 + ((s*4+quad)^(row&7))*16, row&7 == l16&7
    const int aBase = (wm * 128 + l16) * 128;
    const int bBase = (wn * 64  + l16) * 128;
    const int sw0 = ((0 * 4 + quad) ^ r7) * 16;
    const int sw1 = ((1 * 4 + quad) ^ r7) * 16;

    f32x4 acc[8][4] = {};
    short8 aR[4][2], bR[4][2];

    // ---- prologue: stage tiles 0 and 1 (order B,A per tile = in-loop order) ----
#pragma unroll
    for (int i = 0; i < 4; ++i) {
        async_load16(srcB[i],      sm + 32768 + chunk + i * 1024);   // B0 -> buf0.B
        async_load16(srcA[i],      sm + chunk + i * 1024);           // A0 -> buf0.A
    }
#pragma unroll
    for (int i = 0; i < 4; ++i) {
        async_load16(srcB[i] + BK, sm + 65536 + 32768 + chunk + i * 1024);  // B1 -> buf1.B
        async_load16(srcA[i] + BK, sm + 65536 + chunk + i * 1024);          // A1 -> buf1.A
    }
    asm volatile("s_waitcnt vmcnt(8)" ::: "memory");   // A0,B0 landed; B1,A1 in flight
    __builtin_amdgcn_s_barrier();

    for (int kt = 0; kt < NT - 2; ++kt) {
        const char* smA = sm + (kt & 1) * 65536;
        tile_body<1>(acc, aR, bR, smA, smA + 32768, srcA, srcB,
                     (kt + 2) * BK, chunk, aBase, bBase, sw0, sw1);
    }
    {   // tile NT-2 (even -> buf0): no stage, drain for last tile's data
        const char* smA = sm + ((NT - 2) & 1) * 65536;
        tile_body<0>(acc, aR, bR, smA, smA + 32768, srcA, srcB,
                     0, chunk, aBase, bBase, sw0, sw1);
    }
    {   // tile NT-1 (odd -> buf1): no stage, no wait
        const char* smA = sm + ((NT - 1) & 1) * 65536;
        tile_body<-1>(acc, aR, bR, smA, smA + 32768, srcA, srcB,
                      0, chunk, aBase, bBase, sw0, sw1);
    }

    // ---- epilogue: C layout col = lane&15, row = quad*4 + reg ----
    const int h = h0 + wn * 16 + l16;
    const float biv = b_i[h], bfv = b_f[h], bcv = b_c[h], bov = b_o[h];
    const int mb = m0 + wm * 128 + quad * 4;
#pragma unroll
    for (int i = 0; i < 8; ++i) {
#pragma unroll
        for (int r = 0; r < 4; ++r) {
            const int m = mb + i * 16 + r;
            const size_t off = (size_t)m * HID + h;
            const float gi = acc[i][0][r] + biv;
            const float gf = acc[i][1][r] + bfv;
            const float gc = acc[i][2][r] + bcv;
            const float go = acc[i][3][r] + bov;
            const float it = sigm(gi), ft = sigm(gf);
            const float gt = tanh_f(gc), ot = sigm(go);
            const float c = ft * c_prev[off] + it * gt;
            h_out[off] = ot * tanh_f(c);
            c_out[off] = c;
        }
    }
}

extern "C" void kernel_launch(void* const* d_in, const int* in_sizes, int n_in,
                              void* d_out, int out_size, void* d_ws, size_t ws_size,
                              hipStream_t stream) {
    const float* x_t    = (const float*)d_in[0];
    const float* h_prev = (const float*)d_in[1];
    const float* c_prev = (const float*)d_in[2];
    const float* W_i = (const float*)d_in[3];
    const float* b_i = (const float*)d_in[4];
    const float* W_f = (const float*)d_in[5];
    const float* b_f = (const float*)d_in[6];
    const float* W_c = (const float*)d_in[7];
    const float* b_c = (const float*)d_in[8];
    const float* W_o = (const float*)d_in[9];
    const float* b_o = (const float*)d_in[10];
    float* out = (float*)d_out;

    unsigned short* Abf = (unsigned short*)d_ws;                       // 25,165,824 B
    unsigned short* Wbf = (unsigned short*)((char*)d_ws + (size_t)B_DIM * D_DIM * 2);
    // total ws use: 75,497,472 B

    static bool s_attr = false;
    if (!s_attr) {
        (void)hipFuncSetAttribute((const void*)lstm_gemm,
                                  hipFuncAttributeMaxDynamicSharedMemorySize, 131072);
        s_attr = true;
    }

    {
        const int n = (B_DIM * D_DIM + 4 * HID * D_DIM) / 8;   // 4,718,592
        convert_all<<<n / 256, 256, 0, stream>>>(x_t, h_prev, W_i, W_f, W_c, W_o,
                                                 Abf, Wbf);
    }
    dim3 grid(B_DIM / BM, HID / BN);   // 16 x 32
    lstm_gemm<<<grid, 512, 131072, stream>>>(Abf, Wbf, b_i, b_f, b_c, b_o, c_prev,
                                             out, out + (size_t)B_DIM * HID);
}

// Round 4
// 378.736 us; speedup vs baseline: 1.2284x; 1.0174x over previous
//
#include <hip/hip_runtime.h>
#include <stdint.h>

#define B_DIM 4096
#define IN_SZ 1024
#define HID   2048
#define D_DIM 3072   // K = IN_SZ + HID
#define BM 256       // batch rows per block
#define BN 64        // h-columns per block (x4 gates = 256 logical cols)
#define BK 64        // K-step (bf16 elems)
#define NT (D_DIM / BK)   // 48

typedef float  f32x4  __attribute__((ext_vector_type(4)));
typedef short  short8 __attribute__((ext_vector_type(8)));

__device__ __forceinline__ unsigned short f2bf(float f) {
    union { float f; unsigned u; } v; v.f = f;
    unsigned u = v.u + 0x7fffu + ((v.u >> 16) & 1u);   // RNE
    return (unsigned short)(u >> 16);
}

__device__ __forceinline__ void async_load16(const void* g, void* l) {
    __builtin_amdgcn_global_load_lds(
        (const __attribute__((address_space(1))) unsigned int*)g,
        (__attribute__((address_space(3))) unsigned int*)l,
        16, 0, 0);
}

__device__ __forceinline__ float sigm(float x) {
    return 1.0f / (1.0f + __expf(-x));
}
__device__ __forceinline__ float tanh_f(float x) {
    return 1.0f - 2.0f / (__expf(2.0f * x) + 1.0f);
}

// ---- single prepass: concat(x,h)->bf16 [B][D]  and  concat(W_i..W_o)->bf16 [4H][D] ----
__global__ __launch_bounds__(256)
void convert_all(const float* __restrict__ x, const float* __restrict__ h,
                 const float* __restrict__ W0, const float* __restrict__ W1,
                 const float* __restrict__ W2, const float* __restrict__ W3,
                 unsigned short* __restrict__ Abf, unsigned short* __restrict__ Wbf) {
    const int NA = B_DIM * D_DIM / 8;        // 1,572,864
    const int NW = 4 * HID * D_DIM / 8;      // 3,145,728
    int idx = blockIdx.x * blockDim.x + threadIdx.x;
    const float* src;
    unsigned short* dst;
    if (idx < NA) {
        const int C8 = D_DIM / 8;            // 384
        int b = idx / C8, c8 = idx - b * C8;
        src = (c8 < IN_SZ / 8) ? x + (size_t)b * IN_SZ + c8 * 8
                               : h + (size_t)b * HID + (c8 - IN_SZ / 8) * 8;
        dst = Abf + (size_t)idx * 8;
    } else {
        int wi = idx - NA;
        if (wi >= NW) return;
        const int PG = HID * D_DIM / 8;      // 786,432 per gate
        int g = wi / PG, r = wi - g * PG;
        const float* W = (g == 0) ? W0 : (g == 1) ? W1 : (g == 2) ? W2 : W3;
        src = W + (size_t)r * 8;
        dst = Wbf + (size_t)wi * 8;
    }
    float4 v0 = ((const float4*)src)[0];
    float4 v1 = ((const float4*)src)[1];
    short8 o;
    o[0] = (short)f2bf(v0.x); o[1] = (short)f2bf(v0.y);
    o[2] = (short)f2bf(v0.z); o[3] = (short)f2bf(v0.w);
    o[4] = (short)f2bf(v1.x); o[5] = (short)f2bf(v1.y);
    o[6] = (short)f2bf(v1.z); o[7] = (short)f2bf(v1.w);
    *(short8*)dst = o;
}

// ---------- MFMA cluster: 16 MFMAs = m-frags [IB..IB+4) x all 4 n-frags, one k-slice
template <int IB>
__device__ __forceinline__ void mfma16(f32x4 (&acc)[8][4], const short8 (&a)[4],
                                       const short8 (&b)[4]) {
#pragma unroll
    for (int i = 0; i < 4; ++i)
#pragma unroll
        for (int j = 0; j < 4; ++j)
            acc[IB + i][j] = __builtin_amdgcn_mfma_f32_16x16x32_bf16(
                a[i], b[j], acc[IB + i][j], 0, 0, 0);
}

// One K-tile = 4 phases, fragments read ONE PHASE AHEAD (register pipelining):
// each phase issues the ds_reads for phase p+1, then MFMAs phase p. The compiler's
// counted lgkm wait before the MFMAs retires only phase-p frags, so the LDS unit
// services p+1's reads DURING phase p's MFMA. Only 2 barriers per tile:
//   ph3-end: vmcnt(0)+barrier  (stage(kt+1) landed before ph4 reads nxt)
//   tile-end: barrier          (all cur-reads retired before kt+1 overwrites cur)
// MODE: 1 = steady (stage kt+1, read-ahead into nxt), 0 = last tile.
template <int MODE>
__device__ __forceinline__ void tile_body(
    f32x4 (&acc)[8][4],
    short8 (&a0s0)[4], short8 (&a1s0)[4], short8 (&a0s1)[4], short8 (&a1s1)[4],
    short8 (&bs0)[4], short8 (&bs1)[4],
    const char* cur, char* nxt,
    const unsigned short* srcA0, const unsigned short* const* srcB,
    int koff, int chunk, int aBase, int bBase, int sw0, int sw1) {
    const char* curA = cur;
    const char* curB = cur + 32768;

    // ================= phase 1: MFMA m0-3 x s0 =================
    if (MODE) {
#pragma unroll
        for (int i = 0; i < 4; ++i)
            async_load16(srcA0 + i * 8 * D_DIM + koff, nxt + chunk + i * 1024);
    }
#pragma unroll
    for (int i = 0; i < 4; ++i)
        a1s0[i] = *(const short8*)(curA + aBase + (4 + i) * 2048 + sw0);
    bs1[0] = *(const short8*)(curB + bBase + 0 * 2048 + sw1);
    bs1[1] = *(const short8*)(curB + bBase + 1 * 2048 + sw1);
    __builtin_amdgcn_sched_barrier(0);
    __builtin_amdgcn_s_setprio(1);
    mfma16<0>(acc, a0s0, bs0);
    __builtin_amdgcn_s_setprio(0);

    // ================= phase 2: MFMA m4-7 x s0 =================
    if (MODE) {
#pragma unroll
        for (int i = 0; i < 4; ++i)
            async_load16(srcB[i] + koff, nxt + 32768 + chunk + i * 1024);
    }
    bs1[2] = *(const short8*)(curB + bBase + 2 * 2048 + sw1);
    bs1[3] = *(const short8*)(curB + bBase + 3 * 2048 + sw1);
#pragma unroll
    for (int i = 0; i < 4; ++i)
        a0s1[i] = *(const short8*)(curA + aBase + i * 2048 + sw1);
    __builtin_amdgcn_sched_barrier(0);
    __builtin_amdgcn_s_setprio(1);
    mfma16<4>(acc, a1s0, bs0);
    __builtin_amdgcn_s_setprio(0);

    // ================= phase 3: MFMA m0-3 x s1 =================
#pragma unroll
    for (int i = 0; i < 4; ++i)
        a1s1[i] = *(const short8*)(curA + aBase + (4 + i) * 2048 + sw1);
    __builtin_amdgcn_sched_barrier(0);
    __builtin_amdgcn_s_setprio(1);
    mfma16<0>(acc, a0s1, bs1);
    __builtin_amdgcn_s_setprio(0);
    if (MODE) {
        asm volatile("s_waitcnt vmcnt(0)" ::: "memory");   // my stage(kt+1) landed
        __builtin_amdgcn_s_barrier();                      // everyone's landed
        asm volatile("" ::: "memory");                     // no hoisting nxt-reads above
    }

    // ================= phase 4: MFMA m4-7 x s1 =================
    if (MODE) {
#pragma unroll
        for (int i = 0; i < 4; ++i)
            a0s0[i] = *(const short8*)(nxt + aBase + i * 2048 + sw0);
#pragma unroll
        for (int j = 0; j < 4; ++j)
            bs0[j] = *(const short8*)(nxt + 32768 + bBase + j * 2048 + sw0);
    }
    __builtin_amdgcn_sched_barrier(0);
    __builtin_amdgcn_s_setprio(1);
    mfma16<4>(acc, a1s1, bs1);      // compiler lgkm wait here retires all cur-reads
    __builtin_amdgcn_s_setprio(0);
    if (MODE) {
        __builtin_amdgcn_s_barrier();                      // tile end: cur now writable
        asm volatile("" ::: "memory");
    }
}

// ---- fused gate-GEMM + LSTM epilogue, 256x(64h x 4gates) tile, BK=64, 8 waves ----
// Column mapping: col = h_hi*64 + gate*16 + h_lo -> all 4 gates of an (m,h) share a lane.
// LDS: 2 x (A 32K | B 32K) = 128 KiB, [row][64] bf16 rows (128 B) with slot^=row&7 XOR
// swizzle on BOTH the pre-swizzled global staging source and the ds_read offset.
__global__ __launch_bounds__(512, 2)
void lstm_gemm(const unsigned short* __restrict__ Abf,   // [B][D] bf16
               const unsigned short* __restrict__ Wbf,   // [4H][D] bf16
               const float* __restrict__ b_i, const float* __restrict__ b_f,
               const float* __restrict__ b_c, const float* __restrict__ b_o,
               const float* __restrict__ c_prev,
               float* __restrict__ h_out, float* __restrict__ c_out) {
    extern __shared__ char sm[];   // 131072 B

    const int tid  = threadIdx.x;
    const int lane = tid & 63;
    const int wave = tid >> 6;          // 0..7
    const int wm   = wave >> 2;         // 0..1
    const int wn   = wave & 3;          // 0..3
    const int l16  = lane & 15;
    const int quad = lane >> 4;
    const int r7   = l16 & 7;

    const int m0 = blockIdx.x * BM;
    const int h0 = blockIdx.y * BN;

    // staging: instruction (wave,i) covers tile rows (wave*4+i)*8 .. +8 (128 B each)
    const int g8 = lane >> 3;           // row within octet
    const int sl = (lane & 7) ^ g8;     // pre-swizzled source slot (involution)
    const unsigned short* srcA0 = Abf + (size_t)(m0 + wave * 32 + g8) * D_DIM + sl * 8;
    const unsigned short* srcB[4];
#pragma unroll
    for (int i = 0; i < 4; ++i) {
        const int rt = wave * 32 + i * 8 + g8;         // B tile row 0..255
        // B tile row -> W global row: gate=(rt>>4)&3, h = h0 + (rt>>6)*16 + (rt&15)
        const int grow = ((rt >> 4) & 3) * HID + h0 + (rt >> 6) * 16 + (rt & 15);
        srcB[i] = Wbf + (size_t)grow * D_DIM + sl * 8;
    }
    const int chunk = wave * 4096;      // per-wave stage region (+i*1024)

    // ds_read offsets: addr = row*128 + ((s*4+quad)^(row&7))*16, row&7 == l16&7
    const int aBase = (wm * 128 + l16) * 128;
    const int bBase = (wn * 64  + l16) * 128;
    const int sw0 = ((0 * 4 + quad) ^ r7) * 16;
    const int sw1 = ((1 * 4 + quad) ^ r7) * 16;

    f32x4 acc[8][4] = {};
    short8 a0s0[4], a1s0[4], a0s1[4], a1s1[4], bs0[4], bs1[4];

    // ---- prologue: stage tile 0 -> buf0, then pre-issue phase-1 fragments ----
#pragma unroll
    for (int i = 0; i < 4; ++i) {
        async_load16(srcB[i], sm + 32768 + chunk + i * 1024);
        async_load16(srcA0 + i * 8 * D_DIM, sm + chunk + i * 1024);
    }
    asm volatile("s_waitcnt vmcnt(0)" ::: "memory");
    __builtin_amdgcn_s_barrier();
    asm volatile("" ::: "memory");
#pragma unroll
    for (int i = 0; i < 4; ++i)
        a0s0[i] = *(const short8*)(sm + aBase + i * 2048 + sw0);
#pragma unroll
    for (int j = 0; j < 4; ++j)
        bs0[j] = *(const short8*)(sm + 32768 + bBase + j * 2048 + sw0);

    for (int kt = 0; kt < NT - 1; ++kt) {
        const char* cur = sm + (kt & 1) * 65536;
        char* nxt = (char*)sm + ((kt + 1) & 1) * 65536;
        tile_body<1>(acc, a0s0, a1s0, a0s1, a1s1, bs0, bs1, cur, nxt,
                     srcA0, srcB, (kt + 1) * BK, chunk, aBase, bBase, sw0, sw1);
    }
    tile_body<0>(acc, a0s0, a1s0, a0s1, a1s1, bs0, bs1,
                 sm + ((NT - 1) & 1) * 65536, (char*)sm,
                 srcA0, srcB, 0, chunk, aBase, bBase, sw0, sw1);

    // ---- epilogue: C layout col = lane&15, row = quad*4 + reg ----
    const int h = h0 + wn * 16 + l16;
    const float biv = b_i[h], bfv = b_f[h], bcv = b_c[h], bov = b_o[h];
    const int mb = m0 + wm * 128 + quad * 4;
#pragma unroll
    for (int i = 0; i < 8; ++i) {
#pragma unroll
        for (int r = 0; r < 4; ++r) {
            const int m = mb + i * 16 + r;
            const size_t off = (size_t)m * HID + h;
            const float gi = acc[i][0][r] + biv;
            const float gf = acc[i][1][r] + bfv;
            const float gc = acc[i][2][r] + bcv;
            const float go = acc[i][3][r] + bov;
            const float it = sigm(gi), ft = sigm(gf);
            const float gt = tanh_f(gc), ot = sigm(go);
            const float c = ft * c_prev[off] + it * gt;
            h_out[off] = ot * tanh_f(c);
            c_out[off] = c;
        }
    }
}

extern "C" void kernel_launch(void* const* d_in, const int* in_sizes, int n_in,
                              void* d_out, int out_size, void* d_ws, size_t ws_size,
                              hipStream_t stream) {
    const float* x_t    = (const float*)d_in[0];
    const float* h_prev = (const float*)d_in[1];
    const float* c_prev = (const float*)d_in[2];
    const float* W_i = (const float*)d_in[3];
    const float* b_i = (const float*)d_in[4];
    const float* W_f = (const float*)d_in[5];
    const float* b_f = (const float*)d_in[6];
    const float* W_c = (const float*)d_in[7];
    const float* b_c = (const float*)d_in[8];
    const float* W_o = (const float*)d_in[9];
    const float* b_o = (const float*)d_in[10];
    float* out = (float*)d_out;

    unsigned short* Abf = (unsigned short*)d_ws;                       // 25,165,824 B
    unsigned short* Wbf = (unsigned short*)((char*)d_ws + (size_t)B_DIM * D_DIM * 2);
    // total ws use: 75,497,472 B

    static bool s_attr = false;
    if (!s_attr) {
        (void)hipFuncSetAttribute((const void*)lstm_gemm,
                                  hipFuncAttributeMaxDynamicSharedMemorySize, 131072);
        s_attr = true;
    }

    {
        const int n = (B_DIM * D_DIM + 4 * HID * D_DIM) / 8;   // 4,718,592
        convert_all<<<n / 256, 256, 0, stream>>>(x_t, h_prev, W_i, W_f, W_c, W_o,
                                                 Abf, Wbf);
    }
    dim3 grid(B_DIM / BM, HID / BN);   // 16 x 32
    lstm_gemm<<<grid, 512, 131072, stream>>>(Abf, Wbf, b_i, b_f, b_c, b_o, c_prev,
                                             out, out + (size_t)B_DIM * HID);
}